// Round 1
// baseline (610.986 us; speedup 1.0000x reference)
//
#include <hip/hip_runtime.h>
#include <hip/hip_bf16.h>
#include <hip/hip_fp16.h>

// B=2, T=2048, C=1024, H=16, HD=64
typedef _Float16 h8 __attribute__((ext_vector_type(8)));
typedef float fx4 __attribute__((ext_vector_type(4)));

__device__ __forceinline__ void load_lds16(const void* g, void* l) {
  __builtin_amdgcn_global_load_lds((const __attribute__((address_space(1))) void*)g,
                                   (__attribute__((address_space(3))) void*)l, 16, 0, 0);
}

// ---------------- cast f32 -> f16 for x, Wq, Wk, Wv, Wp ----------------
__global__ __launch_bounds__(256) void cast_all(
    const float* __restrict__ x, const float* __restrict__ Wq,
    const float* __restrict__ Wk, const float* __restrict__ Wv,
    const float* __restrict__ Wp,
    _Float16* __restrict__ xh, _Float16* __restrict__ wqkv,
    _Float16* __restrict__ wph) {
  int g = blockIdx.x * 256 + threadIdx.x;  // units of 8 elems, total 1048576
  const float* src; _Float16* dst;
  if (g < 524288)      { size_t o = (size_t)g * 8;            src = x  + o; dst = xh + o; }
  else if (g < 655360) { size_t o = (size_t)(g - 524288) * 8; src = Wq + o; dst = wqkv + o; }
  else if (g < 786432) { size_t o = (size_t)(g - 655360) * 8; src = Wk + o; dst = wqkv + 1048576 + o; }
  else if (g < 917504) { size_t o = (size_t)(g - 786432) * 8; src = Wv + o; dst = wqkv + 2097152 + o; }
  else                 { size_t o = (size_t)(g - 917504) * 8; src = Wp + o; dst = wph + o; }
  float4 a = *(const float4*)(src);
  float4 b = *(const float4*)(src + 4);
  h8 o;
  o[0]=(_Float16)a.x; o[1]=(_Float16)a.y; o[2]=(_Float16)a.z; o[3]=(_Float16)a.w;
  o[4]=(_Float16)b.x; o[5]=(_Float16)b.y; o[6]=(_Float16)b.z; o[7]=(_Float16)b.w;
  *(h8*)dst = o;
}

// ---------------- f16 BT-GEMM: C[m,n] = sum_k A[m,k]*B[n,k] (+bias) ----------------
// 128x128 tile, BK=64, 4 waves (each 64x64), global_load_lds + XOR swizzle.
template<bool OUT16, bool BIAS>
__global__ __launch_bounds__(256) void gemm_bt(
    const _Float16* __restrict__ A, const _Float16* __restrict__ Bm,
    void* __restrict__ Cv, const float* __restrict__ bias,
    int M, int N, int K) {
  __shared__ _Float16 As[8192];  // [128][64] f16, rows 128B, 8 chunks of 16B, chunk^=(row&7)
  __shared__ _Float16 Bs[8192];
  const int tid  = threadIdx.x;
  const int lane = tid & 63, w = tid >> 6;
  const int nb = N >> 7;
  const int m0 = (blockIdx.x / nb) << 7;
  const int n0 = (blockIdx.x % nb) << 7;
  const int wm = (w >> 1) << 6, wn = (w & 1) << 6;
  fx4 acc[4][4] = {};
  const int fbase = w * 4096 + lane * 16;

  for (int k0 = 0; k0 < K; k0 += 64) {
    __syncthreads();
#pragma unroll
    for (int q = 0; q < 4; ++q) {
      int f = fbase + q * 1024;
      int row = f >> 7;
      int sch = ((f >> 4) & 7) ^ (row & 7);
      const _Float16* gA = A  + (size_t)(m0 + row) * K + k0 + sch * 8;
      const _Float16* gB = Bm + (size_t)(n0 + row) * K + k0 + sch * 8;
      load_lds16(gA, (char*)As + w * 4096 + q * 1024);
      load_lds16(gB, (char*)Bs + w * 4096 + q * 1024);
    }
    __syncthreads();

    h8 af[4][2], bf[4][2];
#pragma unroll
    for (int s4 = 0; s4 < 4; ++s4) {
#pragma unroll
      for (int kk = 0; kk < 2; ++kk) {
        int rowa = wm + s4 * 16 + (lane & 15);
        int cha  = (kk * 4 + (lane >> 4)) ^ (rowa & 7);
        af[s4][kk] = *(const h8*)((const char*)As + rowa * 128 + cha * 16);
        int rowb = wn + s4 * 16 + (lane & 15);
        int chb  = (kk * 4 + (lane >> 4)) ^ (rowb & 7);
        bf[s4][kk] = *(const h8*)((const char*)Bs + rowb * 128 + chb * 16);
      }
    }
#pragma unroll
    for (int ms = 0; ms < 4; ++ms)
#pragma unroll
      for (int ns = 0; ns < 4; ++ns) {
        acc[ms][ns] = __builtin_amdgcn_mfma_f32_16x16x32_f16(af[ms][0], bf[ns][0], acc[ms][ns], 0, 0, 0);
        acc[ms][ns] = __builtin_amdgcn_mfma_f32_16x16x32_f16(af[ms][1], bf[ns][1], acc[ms][ns], 0, 0, 0);
      }
  }

#pragma unroll
  for (int ms = 0; ms < 4; ++ms) {
    int row0 = m0 + wm + ms * 16 + ((lane >> 4) << 2);
#pragma unroll
    for (int ns = 0; ns < 4; ++ns) {
      int col = n0 + wn + ns * 16 + (lane & 15);
      float bv = BIAS ? bias[col] : 0.0f;
#pragma unroll
      for (int e = 0; e < 4; ++e) {
        float v = acc[ms][ns][e] + bv;
        if (OUT16) ((_Float16*)Cv)[(size_t)(row0 + e) * N + col] = (_Float16)v;
        else       ((float*)Cv)[(size_t)(row0 + e) * N + col] = v;
      }
    }
  }
}

// ---------------- attention weights: rows = key i, cols = query j ----------------
// grid = B*H*(T/64); block 256 (4 waves x 16 rows). Two-pass recompute softmax, no max
// (logits bounded ~ +-25, exp fits f32 with huge margin).
__global__ __launch_bounds__(256) void attn_weights(
    const _Float16* __restrict__ qkv, float* __restrict__ wout,
    float* __restrict__ wdiag) {
  const int tid = threadIdx.x;
  const int lane = tid & 63, w = tid >> 6;
  const int bid = blockIdx.x;
  const int r = bid & 31;
  const int h = (bid >> 5) & 15;
  const int b = bid >> 9;
  const int i0 = r << 6;
  const int lm = lane & 15, lg = lane >> 4;
  const int d0 = lg << 3;

  const _Float16* kbase = qkv + (size_t)b * 2048 * 3072 + 1024 + h * 64;
  const _Float16* qbase = qkv + (size_t)b * 2048 * 3072 + h * 64;

  const int irow = i0 + w * 16 + lm;
  h8 kf0 = *(const h8*)(kbase + (size_t)irow * 3072 + d0);
  h8 kf1 = *(const h8*)(kbase + (size_t)irow * 3072 + 32 + d0);

  const float slope = exp2f(-0.5f * (float)h);
  const int myrow = i0 + w * 16 + (lg << 2);

  float s[4] = {0.f, 0.f, 0.f, 0.f};

  for (int step = 0; step <= r; ++step) {
    const int j0 = step << 6;
    float psum[4] = {0.f, 0.f, 0.f, 0.f};
#pragma unroll
    for (int sub = 0; sub < 4; ++sub) {
      const int j = j0 + (sub << 4) + lm;
      h8 qf0 = *(const h8*)(qbase + (size_t)j * 3072 + d0);
      h8 qf1 = *(const h8*)(qbase + (size_t)j * 3072 + 32 + d0);
      fx4 acc = {0.f, 0.f, 0.f, 0.f};
      acc = __builtin_amdgcn_mfma_f32_16x16x32_f16(kf0, qf0, acc, 0, 0, 0);
      acc = __builtin_amdgcn_mfma_f32_16x16x32_f16(kf1, qf1, acc, 0, 0, 0);
#pragma unroll
      for (int e = 0; e < 4; ++e) {
        const int i = myrow + e;
        if (j <= i) psum[e] += __expf(acc[e] - slope * (float)(i - j));
      }
    }
#pragma unroll
    for (int e = 0; e < 4; ++e) {
      float v = psum[e];
      v += __shfl_xor(v, 1);
      v += __shfl_xor(v, 2);
      v += __shfl_xor(v, 4);
      v += __shfl_xor(v, 8);
      s[e] += v;
    }
  }

  float rinv[4];
#pragma unroll
  for (int e = 0; e < 4; ++e) rinv[e] = 1.0f / s[e];

  float* wrow = wout + (size_t)(b * 16 + h) * 2048 * 2048;
  float* wd   = wdiag + (b * 16 + h) * 2048;

  for (int step = 0; step <= r; ++step) {
    const int j0 = step << 6;
#pragma unroll
    for (int sub = 0; sub < 4; ++sub) {
      const int j = j0 + (sub << 4) + lm;
      h8 qf0 = *(const h8*)(qbase + (size_t)j * 3072 + d0);
      h8 qf1 = *(const h8*)(qbase + (size_t)j * 3072 + 32 + d0);
      fx4 acc = {0.f, 0.f, 0.f, 0.f};
      acc = __builtin_amdgcn_mfma_f32_16x16x32_f16(kf0, qf0, acc, 0, 0, 0);
      acc = __builtin_amdgcn_mfma_f32_16x16x32_f16(kf1, qf1, acc, 0, 0, 0);
#pragma unroll
      for (int e = 0; e < 4; ++e) {
        const int i = myrow + e;
        float p = (j <= i) ? __expf(acc[e] - slope * (float)(i - j)) * rinv[e] : 0.0f;
        wrow[(size_t)i * 2048 + j] = p;
        if (j == i) wd[i] = p;
      }
    }
  }

  // zero-fill fully-masked tiles (j >= (r+1)*64)
  const int jz0 = (r + 1) << 6;
  if (jz0 < 2048) {
    const int row = tid >> 2, qp = tid & 3;
    const int per = (2048 - jz0) >> 2;  // cols per quarter-thread, multiple of 16
    float* rp = wrow + (size_t)(i0 + row) * 2048 + jz0 + qp * per;
    const float4 z = make_float4(0.f, 0.f, 0.f, 0.f);
    for (int c2 = 0; c2 < per; c2 += 4) *(float4*)(rp + c2) = z;
  }
}

// ---------------- concat[b,t,h*64+d] = wdiag[b,h,t] * v[b,t,h,d] ----------------
__global__ __launch_bounds__(256) void diag_scale(
    const _Float16* __restrict__ qkv, const float* __restrict__ wdiag,
    _Float16* __restrict__ ch) {
  const int g = blockIdx.x * 256 + threadIdx.x;  // 524288 total (8 elems each)
  const int c = (g << 3) & 1023;
  const int bt = g >> 7;
  const int hh = c >> 6;
  const int b = bt >> 11, t = bt & 2047;
  const float wv = wdiag[((b << 4) + hh) * 2048 + t];
  h8 v = *(const h8*)(qkv + (size_t)bt * 3072 + 2048 + c);
  h8 o;
#pragma unroll
  for (int e = 0; e < 8; ++e) o[e] = (_Float16)(wv * (float)v[e]);
  *(h8*)(ch + (size_t)bt * 1024 + c) = o;
}

// ---------------- launch ----------------
extern "C" void kernel_launch(void* const* d_in, const int* in_sizes, int n_in,
                              void* d_out, int out_size, void* d_ws, size_t ws_size,
                              hipStream_t stream) {
  (void)in_sizes; (void)n_in; (void)out_size; (void)ws_size;
  const float* x  = (const float*)d_in[0];
  const float* Wq = (const float*)d_in[1];
  const float* Wk = (const float*)d_in[2];
  const float* Wv = (const float*)d_in[3];
  const float* Wp = (const float*)d_in[4];
  const float* bp = (const float*)d_in[5];

  char* ws = (char*)d_ws;
  _Float16* xh   = (_Float16*)(ws);                 // [4096,1024] f16   8 MB
  _Float16* wqkv = (_Float16*)(ws + 8388608);       // [3072,1024] f16   6 MB
  _Float16* wph  = (_Float16*)(ws + 14680064);      // [1024,1024] f16   2 MB
  _Float16* qkv  = (_Float16*)(ws + 16777216);      // [4096,3072] f16  24 MB
  float*    wdg  = (float*)   (ws + 41943040);      // [B,H,T] f32     256 KB
  _Float16* ch   = (_Float16*)(ws + 42205184);      // [4096,1024] f16   8 MB

  float* out  = (float*)d_out;          // [B,T,C] f32
  float* wout = out + 4194304;          // [B,H,T,T] f32

  cast_all<<<4096, 256, 0, stream>>>(x, Wq, Wk, Wv, Wp, xh, wqkv, wph);
  gemm_bt<true, false><<<32 * 24, 256, 0, stream>>>(xh, wqkv, (void*)qkv, nullptr, 4096, 3072, 1024);
  attn_weights<<<1024, 256, 0, stream>>>(qkv, wout, wdg);
  diag_scale<<<2048, 256, 0, stream>>>(qkv, wdg, ch);
  gemm_bt<false, true><<<32 * 8, 256, 0, stream>>>(ch, wph, (void*)out, bp, 4096, 1024, 1024);
}

// Round 2
// 426.880 us; speedup vs baseline: 1.4313x; 1.4313x over previous
//
#include <hip/hip_runtime.h>
#include <hip/hip_bf16.h>
#include <hip/hip_fp16.h>

// B=2, T=2048, C=1024, H=16, HD=64
typedef _Float16 h8 __attribute__((ext_vector_type(8)));
typedef float fx4 __attribute__((ext_vector_type(4)));

__device__ __forceinline__ void load_lds16(const void* g, void* l) {
  __builtin_amdgcn_global_load_lds((const __attribute__((address_space(1))) void*)g,
                                   (__attribute__((address_space(3))) void*)l, 16, 0, 0);
}

// ---------------- cast f32 -> f16 for x, Wq, Wk, Wv, Wp ----------------
__global__ __launch_bounds__(256) void cast_all(
    const float* __restrict__ x, const float* __restrict__ Wq,
    const float* __restrict__ Wk, const float* __restrict__ Wv,
    const float* __restrict__ Wp,
    _Float16* __restrict__ xh, _Float16* __restrict__ wqkv,
    _Float16* __restrict__ wph) {
  int g = blockIdx.x * 256 + threadIdx.x;  // units of 8 elems, total 1048576
  const float* src; _Float16* dst;
  if (g < 524288)      { size_t o = (size_t)g * 8;            src = x  + o; dst = xh + o; }
  else if (g < 655360) { size_t o = (size_t)(g - 524288) * 8; src = Wq + o; dst = wqkv + o; }
  else if (g < 786432) { size_t o = (size_t)(g - 655360) * 8; src = Wk + o; dst = wqkv + 1048576 + o; }
  else if (g < 917504) { size_t o = (size_t)(g - 786432) * 8; src = Wv + o; dst = wqkv + 2097152 + o; }
  else                 { size_t o = (size_t)(g - 917504) * 8; src = Wp + o; dst = wph + o; }
  float4 a = *(const float4*)(src);
  float4 b = *(const float4*)(src + 4);
  h8 o;
  o[0]=(_Float16)a.x; o[1]=(_Float16)a.y; o[2]=(_Float16)a.z; o[3]=(_Float16)a.w;
  o[4]=(_Float16)b.x; o[5]=(_Float16)b.y; o[6]=(_Float16)b.z; o[7]=(_Float16)b.w;
  *(h8*)dst = o;
}

// ---------------- f16 BT-GEMM: C[m,n] = sum_k A[m,k]*B[n,k] (+bias) ----------------
template<bool OUT16, bool BIAS>
__global__ __launch_bounds__(256) void gemm_bt(
    const _Float16* __restrict__ A, const _Float16* __restrict__ Bm,
    void* __restrict__ Cv, const float* __restrict__ bias,
    int M, int N, int K) {
  __shared__ _Float16 As[8192];  // [128][64] f16, rows 128B, 8 chunks of 16B, chunk^=(row&7)
  __shared__ _Float16 Bs[8192];
  const int tid  = threadIdx.x;
  const int lane = tid & 63, w = tid >> 6;
  const int nb = N >> 7;
  const int m0 = (blockIdx.x / nb) << 7;
  const int n0 = (blockIdx.x % nb) << 7;
  const int wm = (w >> 1) << 6, wn = (w & 1) << 6;
  fx4 acc[4][4] = {};
  const int fbase = w * 4096 + lane * 16;

  for (int k0 = 0; k0 < K; k0 += 64) {
    __syncthreads();
#pragma unroll
    for (int q = 0; q < 4; ++q) {
      int f = fbase + q * 1024;
      int row = f >> 7;
      int sch = ((f >> 4) & 7) ^ (row & 7);
      const _Float16* gA = A  + (size_t)(m0 + row) * K + k0 + sch * 8;
      const _Float16* gB = Bm + (size_t)(n0 + row) * K + k0 + sch * 8;
      load_lds16(gA, (char*)As + w * 4096 + q * 1024);
      load_lds16(gB, (char*)Bs + w * 4096 + q * 1024);
    }
    __syncthreads();

    h8 af[4][2], bf[4][2];
#pragma unroll
    for (int s4 = 0; s4 < 4; ++s4) {
#pragma unroll
      for (int kk = 0; kk < 2; ++kk) {
        int rowa = wm + s4 * 16 + (lane & 15);
        int cha  = (kk * 4 + (lane >> 4)) ^ (rowa & 7);
        af[s4][kk] = *(const h8*)((const char*)As + rowa * 128 + cha * 16);
        int rowb = wn + s4 * 16 + (lane & 15);
        int chb  = (kk * 4 + (lane >> 4)) ^ (rowb & 7);
        bf[s4][kk] = *(const h8*)((const char*)Bs + rowb * 128 + chb * 16);
      }
    }
#pragma unroll
    for (int ms = 0; ms < 4; ++ms)
#pragma unroll
      for (int ns = 0; ns < 4; ++ns) {
        acc[ms][ns] = __builtin_amdgcn_mfma_f32_16x16x32_f16(af[ms][0], bf[ns][0], acc[ms][ns], 0, 0, 0);
        acc[ms][ns] = __builtin_amdgcn_mfma_f32_16x16x32_f16(af[ms][1], bf[ns][1], acc[ms][ns], 0, 0, 0);
      }
  }

#pragma unroll
  for (int ms = 0; ms < 4; ++ms) {
    int row0 = m0 + wm + ms * 16 + ((lane >> 4) << 2);
#pragma unroll
    for (int ns = 0; ns < 4; ++ns) {
      int col = n0 + wn + ns * 16 + (lane & 15);
      float bv = BIAS ? bias[col] : 0.0f;
#pragma unroll
      for (int e = 0; e < 4; ++e) {
        float v = acc[ms][ns][e] + bv;
        if (OUT16) ((_Float16*)Cv)[(size_t)(row0 + e) * N + col] = (_Float16)v;
        else       ((float*)Cv)[(size_t)(row0 + e) * N + col] = v;
      }
    }
  }
}

// ================= tile-parallel attention =================
// grid = B*H*32*32 blocks; tile (it,jt) of 64x64. rows = key i, cols = query j.
// Block: 4 waves, wave w handles key rows i0+w*16..+15 (MFMA A = K-frags),
// cols j0..j0+63 via 4 subs of 16 (MFMA B = Q-frags).

// Pass A: partial row sums -> wpart[((bh*32+it)*64 + iloc)*32 + jt]
__global__ __launch_bounds__(256) void attn_sums(
    const _Float16* __restrict__ qkv, float* __restrict__ wpart) {
  const int bid = blockIdx.x;
  const int jt = bid & 31, it = (bid >> 5) & 31;
  if (jt > it) return;
  const int h = (bid >> 10) & 15, b = bid >> 14;
  const int bh = b * 16 + h;
  const int i0 = it << 6, j0 = jt << 6;
  const int tid = threadIdx.x;
  const int lane = tid & 63, w = tid >> 6;
  const int lm = lane & 15, lg = lane >> 4;
  const int d0 = lg << 3;
  const bool diag = (it == jt);

  const _Float16* kbase = qkv + (size_t)b * 2048 * 3072 + 1024 + h * 64;
  const _Float16* qbase = qkv + (size_t)b * 2048 * 3072 + h * 64;

  const int irow = i0 + w * 16 + lm;
  h8 kf0 = *(const h8*)(kbase + (size_t)irow * 3072 + d0);
  h8 kf1 = *(const h8*)(kbase + (size_t)irow * 3072 + 32 + d0);

  const float slope = exp2f(-0.5f * (float)h);
  const int myrow = i0 + w * 16 + (lg << 2);

  float psum[4] = {0.f, 0.f, 0.f, 0.f};
#pragma unroll
  for (int sub = 0; sub < 4; ++sub) {
    const int j = j0 + (sub << 4) + lm;
    h8 qf0 = *(const h8*)(qbase + (size_t)j * 3072 + d0);
    h8 qf1 = *(const h8*)(qbase + (size_t)j * 3072 + 32 + d0);
    fx4 acc = {0.f, 0.f, 0.f, 0.f};
    acc = __builtin_amdgcn_mfma_f32_16x16x32_f16(kf0, qf0, acc, 0, 0, 0);
    acc = __builtin_amdgcn_mfma_f32_16x16x32_f16(kf1, qf1, acc, 0, 0, 0);
#pragma unroll
    for (int e = 0; e < 4; ++e) {
      const int i = myrow + e;
      if (!diag || j <= i) psum[e] += __expf(acc[e] - slope * (float)(i - j));
    }
  }
#pragma unroll
  for (int e = 0; e < 4; ++e) {
    float v = psum[e];
    v += __shfl_xor(v, 1);
    v += __shfl_xor(v, 2);
    v += __shfl_xor(v, 4);
    v += __shfl_xor(v, 8);
    if (lm == 0)
      wpart[(((size_t)bh * 32 + it) * 64 + w * 16 + (lg << 2) + e) * 32 + jt] = v;
  }
}

// Pass A2: rinv[bh*2048+i] = 1 / sum_{jt<=it} wpart[...]
__global__ __launch_bounds__(256) void sum_reduce(
    const float* __restrict__ wpart, float* __restrict__ rinv) {
  const int idx = blockIdx.x * 256 + threadIdx.x;  // 65536
  const int bh = idx >> 11, i = idx & 2047;
  const int it = i >> 6, iloc = i & 63;
  const float* p = wpart + (((size_t)bh * 32 + it) * 64 + iloc) * 32;
  float s = 0.f;
  for (int jt = 0; jt <= it; ++jt) s += p[jt];
  rinv[idx] = 1.0f / s;
}

// Pass B: write normalized weights (+ diagonal extract, + zero upper tiles)
__global__ __launch_bounds__(256) void attn_write(
    const _Float16* __restrict__ qkv, const float* __restrict__ rinv,
    float* __restrict__ wout, float* __restrict__ wdiag) {
  const int bid = blockIdx.x;
  const int jt = bid & 31, it = (bid >> 5) & 31;
  const int h = (bid >> 10) & 15, b = bid >> 14;
  const int bh = b * 16 + h;
  const int i0 = it << 6, j0 = jt << 6;
  const int tid = threadIdx.x;
  float* wrow = wout + (size_t)bh * 2048 * 2048;

  if (jt > it) {  // fully masked: zero-fill 64x64 f32 tile
    const int row = tid >> 2, qp = tid & 3;
    float* rp = wrow + (size_t)(i0 + row) * 2048 + j0 + qp * 16;
    const float4 z = make_float4(0.f, 0.f, 0.f, 0.f);
#pragma unroll
    for (int c = 0; c < 4; ++c) *(float4*)(rp + c * 4) = z;
    return;
  }

  const int lane = tid & 63, w = tid >> 6;
  const int lm = lane & 15, lg = lane >> 4;
  const int d0 = lg << 3;
  const bool diag = (it == jt);

  const _Float16* kbase = qkv + (size_t)b * 2048 * 3072 + 1024 + h * 64;
  const _Float16* qbase = qkv + (size_t)b * 2048 * 3072 + h * 64;

  const int irow = i0 + w * 16 + lm;
  h8 kf0 = *(const h8*)(kbase + (size_t)irow * 3072 + d0);
  h8 kf1 = *(const h8*)(kbase + (size_t)irow * 3072 + 32 + d0);

  const float slope = exp2f(-0.5f * (float)h);
  const int myrow = i0 + w * 16 + (lg << 2);

  float rv[4];
#pragma unroll
  for (int e = 0; e < 4; ++e) rv[e] = rinv[bh * 2048 + myrow + e];

  float* wd = wdiag + bh * 2048;
#pragma unroll
  for (int sub = 0; sub < 4; ++sub) {
    const int j = j0 + (sub << 4) + lm;
    h8 qf0 = *(const h8*)(qbase + (size_t)j * 3072 + d0);
    h8 qf1 = *(const h8*)(qbase + (size_t)j * 3072 + 32 + d0);
    fx4 acc = {0.f, 0.f, 0.f, 0.f};
    acc = __builtin_amdgcn_mfma_f32_16x16x32_f16(kf0, qf0, acc, 0, 0, 0);
    acc = __builtin_amdgcn_mfma_f32_16x16x32_f16(kf1, qf1, acc, 0, 0, 0);
#pragma unroll
    for (int e = 0; e < 4; ++e) {
      const int i = myrow + e;
      float p = (!diag || j <= i) ? __expf(acc[e] - slope * (float)(i - j)) * rv[e] : 0.0f;
      wrow[(size_t)i * 2048 + j] = p;
      if (diag && j == i) wd[i] = p;
    }
  }
}

// ---------------- concat[b,t,h*64+d] = wdiag[b,h,t] * v[b,t,h,d] ----------------
__global__ __launch_bounds__(256) void diag_scale(
    const _Float16* __restrict__ qkv, const float* __restrict__ wdiag,
    _Float16* __restrict__ ch) {
  const int g = blockIdx.x * 256 + threadIdx.x;  // 524288 total (8 elems each)
  const int c = (g << 3) & 1023;
  const int bt = g >> 7;
  const int hh = c >> 6;
  const int b = bt >> 11, t = bt & 2047;
  const float wv = wdiag[((b << 4) + hh) * 2048 + t];
  h8 v = *(const h8*)(qkv + (size_t)bt * 3072 + 2048 + c);
  h8 o;
#pragma unroll
  for (int e = 0; e < 8; ++e) o[e] = (_Float16)(wv * (float)v[e]);
  *(h8*)(ch + (size_t)bt * 1024 + c) = o;
}

// ---------------- launch ----------------
extern "C" void kernel_launch(void* const* d_in, const int* in_sizes, int n_in,
                              void* d_out, int out_size, void* d_ws, size_t ws_size,
                              hipStream_t stream) {
  (void)in_sizes; (void)n_in; (void)out_size; (void)ws_size;
  const float* x  = (const float*)d_in[0];
  const float* Wq = (const float*)d_in[1];
  const float* Wk = (const float*)d_in[2];
  const float* Wv = (const float*)d_in[3];
  const float* Wp = (const float*)d_in[4];
  const float* bp = (const float*)d_in[5];

  char* ws = (char*)d_ws;
  _Float16* xh   = (_Float16*)(ws);                 // [4096,1024] f16   8 MB
  _Float16* wqkv = (_Float16*)(ws + 8388608);       // [3072,1024] f16   6 MB
  _Float16* wph  = (_Float16*)(ws + 14680064);      // [1024,1024] f16   2 MB
  _Float16* qkv  = (_Float16*)(ws + 16777216);      // [4096,3072] f16  24 MB
  float*    wdg  = (float*)   (ws + 41943040);      // [B,H,T] f32     256 KB
  float*    rinv = (float*)   (ws + 42205184);      // [B,H,T] f32     256 KB
  _Float16* ch   = (_Float16*)(ws + 42467328);      // [4096,1024] f16   8 MB

  float* out  = (float*)d_out;          // [B,T,C] f32
  float* wout = out + 4194304;          // [B,H,T,T] f32
  float* wpart = wout;                  // 16 MB scratch inside wout; pass B overwrites

  cast_all<<<4096, 256, 0, stream>>>(x, Wq, Wk, Wv, Wp, xh, wqkv, wph);
  gemm_bt<true, false><<<32 * 24, 256, 0, stream>>>(xh, wqkv, (void*)qkv, nullptr, 4096, 3072, 1024);
  attn_sums<<<32768, 256, 0, stream>>>(qkv, wpart);
  sum_reduce<<<256, 256, 0, stream>>>(wpart, rinv);
  attn_write<<<32768, 256, 0, stream>>>(qkv, rinv, wout, wdg);
  diag_scale<<<2048, 256, 0, stream>>>(qkv, wdg, ch);
  gemm_bt<false, true><<<32 * 8, 256, 0, stream>>>(ch, wph, (void*)out, bp, 4096, 1024, 1024);
}

// Round 3
// 351.897 us; speedup vs baseline: 1.7363x; 1.2131x over previous
//
#include <hip/hip_runtime.h>
#include <hip/hip_bf16.h>
#include <hip/hip_fp16.h>

// B=2, T=2048, C=1024, H=16, HD=64
typedef _Float16 h8 __attribute__((ext_vector_type(8)));
typedef float fx4 __attribute__((ext_vector_type(4)));

__device__ __forceinline__ void load_lds16(const void* g, void* l) {
  __builtin_amdgcn_global_load_lds((const __attribute__((address_space(1))) void*)g,
                                   (__attribute__((address_space(3))) void*)l, 16, 0, 0);
}

// ---------------- cast f32 -> f16 for x, Wq, Wk, Wv, Wp ----------------
__global__ __launch_bounds__(256) void cast_all(
    const float* __restrict__ x, const float* __restrict__ Wq,
    const float* __restrict__ Wk, const float* __restrict__ Wv,
    const float* __restrict__ Wp,
    _Float16* __restrict__ xh, _Float16* __restrict__ wqkv,
    _Float16* __restrict__ wph) {
  int g = blockIdx.x * 256 + threadIdx.x;  // units of 8 elems, total 1048576
  const float* src; _Float16* dst;
  if (g < 524288)      { size_t o = (size_t)g * 8;            src = x  + o; dst = xh + o; }
  else if (g < 655360) { size_t o = (size_t)(g - 524288) * 8; src = Wq + o; dst = wqkv + o; }
  else if (g < 786432) { size_t o = (size_t)(g - 655360) * 8; src = Wk + o; dst = wqkv + 1048576 + o; }
  else if (g < 917504) { size_t o = (size_t)(g - 786432) * 8; src = Wv + o; dst = wqkv + 2097152 + o; }
  else                 { size_t o = (size_t)(g - 917504) * 8; src = Wp + o; dst = wph + o; }
  float4 a = *(const float4*)(src);
  float4 b = *(const float4*)(src + 4);
  h8 o;
  o[0]=(_Float16)a.x; o[1]=(_Float16)a.y; o[2]=(_Float16)a.z; o[3]=(_Float16)a.w;
  o[4]=(_Float16)b.x; o[5]=(_Float16)b.y; o[6]=(_Float16)b.z; o[7]=(_Float16)b.w;
  *(h8*)dst = o;
}

// ---------------- f16 BT-GEMM: C[m,n] = sum_k A[m,k]*B[n,k] (+bias) ----------------
template<bool OUT16, bool BIAS>
__global__ __launch_bounds__(256) void gemm_bt(
    const _Float16* __restrict__ A, const _Float16* __restrict__ Bm,
    void* __restrict__ Cv, const float* __restrict__ bias,
    int M, int N, int K) {
  __shared__ _Float16 As[8192];  // [128][64] f16, rows 128B, 8 chunks of 16B, chunk^=(row&7)
  __shared__ _Float16 Bs[8192];
  const int tid  = threadIdx.x;
  const int lane = tid & 63, w = tid >> 6;
  const int nb = N >> 7;
  const int m0 = (blockIdx.x / nb) << 7;
  const int n0 = (blockIdx.x % nb) << 7;
  const int wm = (w >> 1) << 6, wn = (w & 1) << 6;
  fx4 acc[4][4] = {};
  const int fbase = w * 4096 + lane * 16;

  for (int k0 = 0; k0 < K; k0 += 64) {
    __syncthreads();
#pragma unroll
    for (int q = 0; q < 4; ++q) {
      int f = fbase + q * 1024;
      int row = f >> 7;
      int sch = ((f >> 4) & 7) ^ (row & 7);
      const _Float16* gA = A  + (size_t)(m0 + row) * K + k0 + sch * 8;
      const _Float16* gB = Bm + (size_t)(n0 + row) * K + k0 + sch * 8;
      load_lds16(gA, (char*)As + w * 4096 + q * 1024);
      load_lds16(gB, (char*)Bs + w * 4096 + q * 1024);
    }
    __syncthreads();

    h8 af[4][2], bf[4][2];
#pragma unroll
    for (int s4 = 0; s4 < 4; ++s4) {
#pragma unroll
      for (int kk = 0; kk < 2; ++kk) {
        int rowa = wm + s4 * 16 + (lane & 15);
        int cha  = (kk * 4 + (lane >> 4)) ^ (rowa & 7);
        af[s4][kk] = *(const h8*)((const char*)As + rowa * 128 + cha * 16);
        int rowb = wn + s4 * 16 + (lane & 15);
        int chb  = (kk * 4 + (lane >> 4)) ^ (rowb & 7);
        bf[s4][kk] = *(const h8*)((const char*)Bs + rowb * 128 + chb * 16);
      }
    }
#pragma unroll
    for (int ms = 0; ms < 4; ++ms)
#pragma unroll
      for (int ns = 0; ns < 4; ++ns) {
        acc[ms][ns] = __builtin_amdgcn_mfma_f32_16x16x32_f16(af[ms][0], bf[ns][0], acc[ms][ns], 0, 0, 0);
        acc[ms][ns] = __builtin_amdgcn_mfma_f32_16x16x32_f16(af[ms][1], bf[ns][1], acc[ms][ns], 0, 0, 0);
      }
  }

#pragma unroll
  for (int ms = 0; ms < 4; ++ms) {
    int row0 = m0 + wm + ms * 16 + ((lane >> 4) << 2);
#pragma unroll
    for (int ns = 0; ns < 4; ++ns) {
      int col = n0 + wn + ns * 16 + (lane & 15);
      float bv = BIAS ? bias[col] : 0.0f;
#pragma unroll
      for (int e = 0; e < 4; ++e) {
        float v = acc[ms][ns][e] + bv;
        if (OUT16) ((_Float16*)Cv)[(size_t)(row0 + e) * N + col] = (_Float16)v;
        else       ((float*)Cv)[(size_t)(row0 + e) * N + col] = v;
      }
    }
  }
}

// ================= tile-parallel attention =================
// tile (it,jt) of 64x64; rows = key i, cols = query j.
// Block: 4 waves, wave w handles key rows i0+w*16..+15 (MFMA A = K-frags),
// cols j0..j0+63 via 4 subs of 16 (MFMA B = Q-frags).

// Pass A: only lower-triangle tiles launched (528 per bh).
// wpart[((bh*32+it)*64 + iloc)*32 + jt] = partial row sums
__global__ __launch_bounds__(256) void attn_sums(
    const _Float16* __restrict__ qkv, float* __restrict__ wpart) {
  const int u = blockIdx.x % 528;
  const int bh = blockIdx.x / 528;
  int it = (int)((sqrtf(8.0f * (float)u + 1.0f) - 1.0f) * 0.5f);
  while ((it + 1) * (it + 2) / 2 <= u) ++it;
  while (it * (it + 1) / 2 > u) --it;
  const int jt = u - it * (it + 1) / 2;
  const int b = bh >> 4, h = bh & 15;
  const int i0 = it << 6, j0 = jt << 6;
  const int tid = threadIdx.x;
  const int lane = tid & 63, w = tid >> 6;
  const int lm = lane & 15, lg = lane >> 4;
  const int d0 = lg << 3;
  const bool diag = (it == jt);

  const _Float16* kbase = qkv + (size_t)b * 2048 * 3072 + 1024 + h * 64;
  const _Float16* qbase = qkv + (size_t)b * 2048 * 3072 + h * 64;

  const int irow = i0 + w * 16 + lm;
  h8 kf0 = *(const h8*)(kbase + (size_t)irow * 3072 + d0);
  h8 kf1 = *(const h8*)(kbase + (size_t)irow * 3072 + 32 + d0);

  const float slope = exp2f(-0.5f * (float)h);
  const int myrow = i0 + w * 16 + (lg << 2);

  float psum[4] = {0.f, 0.f, 0.f, 0.f};
#pragma unroll
  for (int sub = 0; sub < 4; ++sub) {
    const int j = j0 + (sub << 4) + lm;
    h8 qf0 = *(const h8*)(qbase + (size_t)j * 3072 + d0);
    h8 qf1 = *(const h8*)(qbase + (size_t)j * 3072 + 32 + d0);
    fx4 acc = {0.f, 0.f, 0.f, 0.f};
    acc = __builtin_amdgcn_mfma_f32_16x16x32_f16(kf0, qf0, acc, 0, 0, 0);
    acc = __builtin_amdgcn_mfma_f32_16x16x32_f16(kf1, qf1, acc, 0, 0, 0);
#pragma unroll
    for (int e = 0; e < 4; ++e) {
      const int i = myrow + e;
      if (!diag || j <= i) psum[e] += __expf(acc[e] - slope * (float)(i - j));
    }
  }
#pragma unroll
  for (int e = 0; e < 4; ++e) {
    float v = psum[e];
    v += __shfl_xor(v, 1);
    v += __shfl_xor(v, 2);
    v += __shfl_xor(v, 4);
    v += __shfl_xor(v, 8);
    if (lm == 0)
      wpart[(((size_t)bh * 32 + it) * 64 + w * 16 + (lg << 2) + e) * 32 + jt] = v;
  }
}

// Pass A2: rinv[bh*2048+i] = 1 / sum_{jt<=it} wpart[...]
__global__ __launch_bounds__(256) void sum_reduce(
    const float* __restrict__ wpart, float* __restrict__ rinv) {
  const int idx = blockIdx.x * 256 + threadIdx.x;  // 65536
  const int bh = idx >> 11, i = idx & 2047;
  const int it = i >> 6, iloc = i & 63;
  const float* p = wpart + (((size_t)bh * 32 + it) * 64 + iloc) * 32;
  float s = 0.f;
  for (int jt = 0; jt <= it; ++jt) s += p[jt];
  rinv[idx] = 1.0f / s;
}

// Pass B: write normalized weights (+ diagonal extract, + zero upper tiles).
// LDS bounce so global stores are full 256B row segments (float4/lane).
__global__ __launch_bounds__(256) void attn_write(
    const _Float16* __restrict__ qkv, const float* __restrict__ rinv,
    float* __restrict__ wout, float* __restrict__ wdiag) {
  const int bid = blockIdx.x;
  const int jt = bid & 31, it = (bid >> 5) & 31;
  const int h = (bid >> 10) & 15, b = bid >> 14;
  const int bh = b * 16 + h;
  const int i0 = it << 6, j0 = jt << 6;
  const int tid = threadIdx.x;
  float* wrow = wout + (size_t)bh * 2048 * 2048;

  if (jt > it) {  // fully masked: zero-fill 64x64 f32 tile, 256B/4-lane segments
    const int row = tid >> 2, qp = tid & 3;
    float* rp = wrow + (size_t)(i0 + row) * 2048 + j0 + qp * 16;
    const float4 z = make_float4(0.f, 0.f, 0.f, 0.f);
#pragma unroll
    for (int c = 0; c < 4; ++c) *(float4*)(rp + c * 4) = z;
    return;
  }

  __shared__ float tile[64 * 68];  // stride 68: aligned float4 rows, ~2-way banks max

  const int lane = tid & 63, w = tid >> 6;
  const int lm = lane & 15, lg = lane >> 4;
  const int d0 = lg << 3;
  const bool diag = (it == jt);

  const _Float16* kbase = qkv + (size_t)b * 2048 * 3072 + 1024 + h * 64;
  const _Float16* qbase = qkv + (size_t)b * 2048 * 3072 + h * 64;

  const int irow = i0 + w * 16 + lm;
  h8 kf0 = *(const h8*)(kbase + (size_t)irow * 3072 + d0);
  h8 kf1 = *(const h8*)(kbase + (size_t)irow * 3072 + 32 + d0);

  const float slope = exp2f(-0.5f * (float)h);
  const int myrow = i0 + w * 16 + (lg << 2);

  float rv[4];
#pragma unroll
  for (int e = 0; e < 4; ++e) rv[e] = rinv[bh * 2048 + myrow + e];

  float* wd = wdiag + bh * 2048;
#pragma unroll
  for (int sub = 0; sub < 4; ++sub) {
    const int j = j0 + (sub << 4) + lm;
    h8 qf0 = *(const h8*)(qbase + (size_t)j * 3072 + d0);
    h8 qf1 = *(const h8*)(qbase + (size_t)j * 3072 + 32 + d0);
    fx4 acc = {0.f, 0.f, 0.f, 0.f};
    acc = __builtin_amdgcn_mfma_f32_16x16x32_f16(kf0, qf0, acc, 0, 0, 0);
    acc = __builtin_amdgcn_mfma_f32_16x16x32_f16(kf1, qf1, acc, 0, 0, 0);
#pragma unroll
    for (int e = 0; e < 4; ++e) {
      const int i = myrow + e;
      float p = (!diag || j <= i) ? __expf(acc[e] - slope * (float)(i - j)) * rv[e] : 0.0f;
      tile[(w * 16 + (lg << 2) + e) * 68 + (sub << 4) + lm] = p;
      if (diag && j == i) wd[i] = p;
    }
  }
  __syncthreads();

  // coalesced store: wave w -> rows w*16..w*16+15, float4 per lane
  const int rl = lane >> 4, cw = (lane & 15) << 2;
#pragma unroll
  for (int q = 0; q < 4; ++q) {
    const int r = w * 16 + q * 4 + rl;
    float4 v = *(const float4*)&tile[r * 68 + cw];
    *(float4*)(wrow + (size_t)(i0 + r) * 2048 + j0 + cw) = v;
  }
}

// ---------------- concat[b,t,h*64+d] = wdiag[b,h,t] * v[b,t,h,d] ----------------
__global__ __launch_bounds__(256) void diag_scale(
    const _Float16* __restrict__ qkv, const float* __restrict__ wdiag,
    _Float16* __restrict__ ch) {
  const int g = blockIdx.x * 256 + threadIdx.x;  // 524288 total (8 elems each)
  const int c = (g << 3) & 1023;
  const int bt = g >> 7;
  const int hh = c >> 6;
  const int b = bt >> 11, t = bt & 2047;
  const float wv = wdiag[((b << 4) + hh) * 2048 + t];
  h8 v = *(const h8*)(qkv + (size_t)bt * 3072 + 2048 + c);
  h8 o;
#pragma unroll
  for (int e = 0; e < 8; ++e) o[e] = (_Float16)(wv * (float)v[e]);
  *(h8*)(ch + (size_t)bt * 1024 + c) = o;
}

// ---------------- launch ----------------
extern "C" void kernel_launch(void* const* d_in, const int* in_sizes, int n_in,
                              void* d_out, int out_size, void* d_ws, size_t ws_size,
                              hipStream_t stream) {
  (void)in_sizes; (void)n_in; (void)out_size; (void)ws_size;
  const float* x  = (const float*)d_in[0];
  const float* Wq = (const float*)d_in[1];
  const float* Wk = (const float*)d_in[2];
  const float* Wv = (const float*)d_in[3];
  const float* Wp = (const float*)d_in[4];
  const float* bp = (const float*)d_in[5];

  char* ws = (char*)d_ws;
  _Float16* xh   = (_Float16*)(ws);                 // [4096,1024] f16   8 MB
  _Float16* wqkv = (_Float16*)(ws + 8388608);       // [3072,1024] f16   6 MB
  _Float16* wph  = (_Float16*)(ws + 14680064);      // [1024,1024] f16   2 MB
  _Float16* qkv  = (_Float16*)(ws + 16777216);      // [4096,3072] f16  24 MB
  float*    wdg  = (float*)   (ws + 41943040);      // [B,H,T] f32     256 KB
  float*    rinv = (float*)   (ws + 42205184);      // [B,H,T] f32     256 KB
  _Float16* ch   = (_Float16*)(ws + 42467328);      // [4096,1024] f16   8 MB

  float* out  = (float*)d_out;          // [B,T,C] f32
  float* wout = out + 4194304;          // [B,H,T,T] f32
  float* wpart = wout;                  // 16 MB scratch inside wout; pass B overwrites

  cast_all<<<4096, 256, 0, stream>>>(x, Wq, Wk, Wv, Wp, xh, wqkv, wph);
  gemm_bt<true, false><<<32 * 24, 256, 0, stream>>>(xh, wqkv, (void*)qkv, nullptr, 4096, 3072, 1024);
  attn_sums<<<528 * 32, 256, 0, stream>>>(qkv, wpart);
  sum_reduce<<<256, 256, 0, stream>>>(wpart, rinv);
  attn_write<<<32768, 256, 0, stream>>>(qkv, rinv, wout, wdg);
  diag_scale<<<2048, 256, 0, stream>>>(qkv, wdg, ch);
  gemm_bt<false, true><<<32 * 8, 256, 0, stream>>>(ch, wph, (void*)out, bp, 4096, 1024, 1024);
}

// Round 5
// 274.330 us; speedup vs baseline: 2.2272x; 1.2827x over previous
//
#include <hip/hip_runtime.h>
#include <hip/hip_bf16.h>
#include <hip/hip_fp16.h>

// B=2, T=2048, C=1024, H=16, HD=64
typedef _Float16 h8 __attribute__((ext_vector_type(8)));
typedef float fx4 __attribute__((ext_vector_type(4)));

__device__ __forceinline__ void load_lds16(const void* g, void* l) {
  __builtin_amdgcn_global_load_lds((const __attribute__((address_space(1))) void*)g,
                                   (__attribute__((address_space(3))) void*)l, 16, 0, 0);
}

// ---------------- cast f32 -> f16 for x, Wq, Wk, Wv, Wp ----------------
__global__ __launch_bounds__(256) void cast_all(
    const float* __restrict__ x, const float* __restrict__ Wq,
    const float* __restrict__ Wk, const float* __restrict__ Wv,
    const float* __restrict__ Wp,
    _Float16* __restrict__ xh, _Float16* __restrict__ wqkv,
    _Float16* __restrict__ wph) {
  int g = blockIdx.x * 256 + threadIdx.x;  // units of 8 elems, total 1048576
  const float* src; _Float16* dst;
  if (g < 524288)      { size_t o = (size_t)g * 8;            src = x  + o; dst = xh + o; }
  else if (g < 655360) { size_t o = (size_t)(g - 524288) * 8; src = Wq + o; dst = wqkv + o; }
  else if (g < 786432) { size_t o = (size_t)(g - 655360) * 8; src = Wk + o; dst = wqkv + 1048576 + o; }
  else if (g < 917504) { size_t o = (size_t)(g - 786432) * 8; src = Wv + o; dst = wqkv + 2097152 + o; }
  else                 { size_t o = (size_t)(g - 917504) * 8; src = Wp + o; dst = wph + o; }
  float4 a = *(const float4*)(src);
  float4 b = *(const float4*)(src + 4);
  h8 o;
  o[0]=(_Float16)a.x; o[1]=(_Float16)a.y; o[2]=(_Float16)a.z; o[3]=(_Float16)a.w;
  o[4]=(_Float16)b.x; o[5]=(_Float16)b.y; o[6]=(_Float16)b.z; o[7]=(_Float16)b.w;
  *(h8*)dst = o;
}

// ---------------- f16 BT-GEMM: C[m,n] = sum_k A[m,k]*B[n,k] (+bias) ----------------
template<bool OUT16, bool BIAS>
__global__ __launch_bounds__(256) void gemm_bt(
    const _Float16* __restrict__ A, const _Float16* __restrict__ Bm,
    void* __restrict__ Cv, const float* __restrict__ bias,
    int M, int N, int K) {
  __shared__ _Float16 As[8192];  // [128][64] f16, rows 128B, 8 chunks of 16B, chunk^=(row&7)
  __shared__ _Float16 Bs[8192];
  const int tid  = threadIdx.x;
  const int lane = tid & 63, w = tid >> 6;
  const int nb = N >> 7;
  const int m0 = (blockIdx.x / nb) << 7;
  const int n0 = (blockIdx.x % nb) << 7;
  const int wm = (w >> 1) << 6, wn = (w & 1) << 6;
  fx4 acc[4][4] = {};
  const int fbase = w * 4096 + lane * 16;

  for (int k0 = 0; k0 < K; k0 += 64) {
    __syncthreads();
#pragma unroll
    for (int q = 0; q < 4; ++q) {
      int f = fbase + q * 1024;
      int row = f >> 7;
      int sch = ((f >> 4) & 7) ^ (row & 7);
      const _Float16* gA = A  + (size_t)(m0 + row) * K + k0 + sch * 8;
      const _Float16* gB = Bm + (size_t)(n0 + row) * K + k0 + sch * 8;
      load_lds16(gA, (char*)As + w * 4096 + q * 1024);
      load_lds16(gB, (char*)Bs + w * 4096 + q * 1024);
    }
    __syncthreads();

    h8 af[4][2], bf[4][2];
#pragma unroll
    for (int s4 = 0; s4 < 4; ++s4) {
#pragma unroll
      for (int kk = 0; kk < 2; ++kk) {
        int rowa = wm + s4 * 16 + (lane & 15);
        int cha  = (kk * 4 + (lane >> 4)) ^ (rowa & 7);
        af[s4][kk] = *(const h8*)((const char*)As + rowa * 128 + cha * 16);
        int rowb = wn + s4 * 16 + (lane & 15);
        int chb  = (kk * 4 + (lane >> 4)) ^ (rowb & 7);
        bf[s4][kk] = *(const h8*)((const char*)Bs + rowb * 128 + chb * 16);
      }
    }
#pragma unroll
    for (int ms = 0; ms < 4; ++ms)
#pragma unroll
      for (int ns = 0; ns < 4; ++ns) {
        acc[ms][ns] = __builtin_amdgcn_mfma_f32_16x16x32_f16(af[ms][0], bf[ns][0], acc[ms][ns], 0, 0, 0);
        acc[ms][ns] = __builtin_amdgcn_mfma_f32_16x16x32_f16(af[ms][1], bf[ns][1], acc[ms][ns], 0, 0, 0);
      }
  }

#pragma unroll
  for (int ms = 0; ms < 4; ++ms) {
    int row0 = m0 + wm + ms * 16 + ((lane >> 4) << 2);
#pragma unroll
    for (int ns = 0; ns < 4; ++ns) {
      int col = n0 + wn + ns * 16 + (lane & 15);
      float bv = BIAS ? bias[col] : 0.0f;
#pragma unroll
      for (int e = 0; e < 4; ++e) {
        float v = acc[ms][ns][e] + bv;
        if (OUT16) ((_Float16*)Cv)[(size_t)(row0 + e) * N + col] = (_Float16)v;
        else       ((float*)Cv)[(size_t)(row0 + e) * N + col] = v;
      }
    }
  }
}

// ================= tile-parallel attention =================
// tile (it,jt) of 64x64; rows = key i, cols = query j.
// Block: 4 waves, wave w handles key rows i0+w*16..+15 (MFMA A = K-frags),
// cols j0..j0+63 via 4 subs of 16 (MFMA B = Q-frags).

// Pass A: only lower-triangle tiles launched (528 per bh).
// wpart[((bh*32+it)*64 + iloc)*32 + jt] = partial row sums
__global__ __launch_bounds__(256) void attn_sums(
    const _Float16* __restrict__ qkv, float* __restrict__ wpart) {
  // XCD-chunked swizzle: 16896 blocks = 8 * 2112
  const int bid = (blockIdx.x & 7) * 2112 + (blockIdx.x >> 3);
  const int u = bid % 528;
  const int bh = bid / 528;
  int it = (int)((sqrtf(8.0f * (float)u + 1.0f) - 1.0f) * 0.5f);
  while ((it + 1) * (it + 2) / 2 <= u) ++it;
  while (it * (it + 1) / 2 > u) --it;
  const int jt = u - it * (it + 1) / 2;
  const int b = bh >> 4, h = bh & 15;
  const int i0 = it << 6, j0 = jt << 6;
  const int tid = threadIdx.x;
  const int lane = tid & 63, w = tid >> 6;
  const int lm = lane & 15, lg = lane >> 4;
  const int d0 = lg << 3;
  const bool diag = (it == jt);

  const _Float16* kbase = qkv + (size_t)b * 2048 * 3072 + 1024 + h * 64;
  const _Float16* qbase = qkv + (size_t)b * 2048 * 3072 + h * 64;

  const int irow = i0 + w * 16 + lm;
  h8 kf0 = *(const h8*)(kbase + (size_t)irow * 3072 + d0);
  h8 kf1 = *(const h8*)(kbase + (size_t)irow * 3072 + 32 + d0);

  const float slope = exp2f(-0.5f * (float)h);
  const int myrow = i0 + w * 16 + (lg << 2);

  float psum[4] = {0.f, 0.f, 0.f, 0.f};
#pragma unroll
  for (int sub = 0; sub < 4; ++sub) {
    const int j = j0 + (sub << 4) + lm;
    h8 qf0 = *(const h8*)(qbase + (size_t)j * 3072 + d0);
    h8 qf1 = *(const h8*)(qbase + (size_t)j * 3072 + 32 + d0);
    fx4 acc = {0.f, 0.f, 0.f, 0.f};
    acc = __builtin_amdgcn_mfma_f32_16x16x32_f16(kf0, qf0, acc, 0, 0, 0);
    acc = __builtin_amdgcn_mfma_f32_16x16x32_f16(kf1, qf1, acc, 0, 0, 0);
#pragma unroll
    for (int e = 0; e < 4; ++e) {
      const int i = myrow + e;
      if (!diag || j <= i) psum[e] += __expf(acc[e] - slope * (float)(i - j));
    }
  }
#pragma unroll
  for (int e = 0; e < 4; ++e) {
    float v = psum[e];
    v += __shfl_xor(v, 1);
    v += __shfl_xor(v, 2);
    v += __shfl_xor(v, 4);
    v += __shfl_xor(v, 8);
    if (lm == 0)
      wpart[(((size_t)bh * 32 + it) * 64 + w * 16 + (lg << 2) + e) * 32 + jt] = v;
  }
}

// Pass A2: rinv[bh*2048+i] = 1 / sum_{jt<=it} wpart[...]
__global__ __launch_bounds__(256) void sum_reduce(
    const float* __restrict__ wpart, float* __restrict__ rinv) {
  const int idx = blockIdx.x * 256 + threadIdx.x;  // 65536
  const int bh = idx >> 11, i = idx & 2047;
  const int it = i >> 6, iloc = i & 63;
  const float* p = wpart + (((size_t)bh * 32 + it) * 64 + iloc) * 32;
  float s = 0.f;
  for (int jt = 0; jt <= it; ++jt) s += p[jt];
  rinv[idx] = 1.0f / s;
}

// Pass B: write normalized weights (+ diagonal extract, + zero upper tiles).
// LDS bounce (wave-private rows -> no barrier); nontemporal coalesced stores.
__global__ __launch_bounds__(256) void attn_write(
    const _Float16* __restrict__ qkv, const float* __restrict__ rinv,
    float* __restrict__ wout, float* __restrict__ wdiag) {
  // XCD-chunked swizzle: 32768 blocks = 8 * 4096
  const int bid = (blockIdx.x & 7) * 4096 + (blockIdx.x >> 3);
  const int jt = bid & 31, it = (bid >> 5) & 31;
  const int h = (bid >> 10) & 15, b = bid >> 14;
  const int bh = b * 16 + h;
  const int i0 = it << 6, j0 = jt << 6;
  const int tid = threadIdx.x;
  const int lane = tid & 63, w = tid >> 6;
  float* wrow = wout + (size_t)bh * 2048 * 2048;

  const int rl = lane >> 4, cw = (lane & 15) << 2;

  if (jt > it) {  // fully masked: zero-fill, full-row 256B segments per 16 lanes
    const fx4 z = {0.f, 0.f, 0.f, 0.f};
#pragma unroll
    for (int q = 0; q < 4; ++q) {
      const int r = w * 16 + q * 4 + rl;
      __builtin_nontemporal_store(z, (fx4*)(wrow + (size_t)(i0 + r) * 2048 + j0 + cw));
    }
    return;
  }

  __shared__ float tile[64 * 68];  // stride 68: aligned float4 rows, ~2-way banks max

  const int lm = lane & 15, lg = lane >> 4;
  const int d0 = lg << 3;
  const bool diag = (it == jt);

  const _Float16* kbase = qkv + (size_t)b * 2048 * 3072 + 1024 + h * 64;
  const _Float16* qbase = qkv + (size_t)b * 2048 * 3072 + h * 64;

  const int irow = i0 + w * 16 + lm;
  h8 kf0 = *(const h8*)(kbase + (size_t)irow * 3072 + d0);
  h8 kf1 = *(const h8*)(kbase + (size_t)irow * 3072 + 32 + d0);

  const float slope = exp2f(-0.5f * (float)h);
  const int myrow = i0 + w * 16 + (lg << 2);

  float rv[4];
#pragma unroll
  for (int e = 0; e < 4; ++e) rv[e] = rinv[bh * 2048 + myrow + e];

  float* wd = wdiag + bh * 2048;
#pragma unroll
  for (int sub = 0; sub < 4; ++sub) {
    const int j = j0 + (sub << 4) + lm;
    h8 qf0 = *(const h8*)(qbase + (size_t)j * 3072 + d0);
    h8 qf1 = *(const h8*)(qbase + (size_t)j * 3072 + 32 + d0);
    fx4 acc = {0.f, 0.f, 0.f, 0.f};
    acc = __builtin_amdgcn_mfma_f32_16x16x32_f16(kf0, qf0, acc, 0, 0, 0);
    acc = __builtin_amdgcn_mfma_f32_16x16x32_f16(kf1, qf1, acc, 0, 0, 0);
#pragma unroll
    for (int e = 0; e < 4; ++e) {
      const int i = myrow + e;
      float p = (!diag || j <= i) ? __expf(acc[e] - slope * (float)(i - j)) * rv[e] : 0.0f;
      tile[(w * 16 + (lg << 2) + e) * 68 + (sub << 4) + lm] = p;
      if (diag && j == i) wd[i] = p;
    }
  }
  // No __syncthreads: wave w wrote exactly rows w*16..w*16+15; it alone reads them.
  // Compiler inserts lgkmcnt wait for the LDS RAW hazard within the wave.
#pragma unroll
  for (int q = 0; q < 4; ++q) {
    const int r = w * 16 + q * 4 + rl;
    fx4 v = *(const fx4*)&tile[r * 68 + cw];
    __builtin_nontemporal_store(v, (fx4*)(wrow + (size_t)(i0 + r) * 2048 + j0 + cw));
  }
}

// ---------------- concat[b,t,h*64+d] = wdiag[b,h,t] * v[b,t,h,d] ----------------
__global__ __launch_bounds__(256) void diag_scale(
    const _Float16* __restrict__ qkv, const float* __restrict__ wdiag,
    _Float16* __restrict__ ch) {
  const int g = blockIdx.x * 256 + threadIdx.x;  // 524288 total (8 elems each)
  const int c = (g << 3) & 1023;
  const int bt = g >> 7;
  const int hh = c >> 6;
  const int b = bt >> 11, t = bt & 2047;
  const float wv = wdiag[((b << 4) + hh) * 2048 + t];
  h8 v = *(const h8*)(qkv + (size_t)bt * 3072 + 2048 + c);
  h8 o;
#pragma unroll
  for (int e = 0; e < 8; ++e) o[e] = (_Float16)(wv * (float)v[e]);
  *(h8*)(ch + (size_t)bt * 1024 + c) = o;
}

// ---------------- launch ----------------
extern "C" void kernel_launch(void* const* d_in, const int* in_sizes, int n_in,
                              void* d_out, int out_size, void* d_ws, size_t ws_size,
                              hipStream_t stream) {
  (void)in_sizes; (void)n_in; (void)out_size; (void)ws_size;
  const float* x  = (const float*)d_in[0];
  const float* Wq = (const float*)d_in[1];
  const float* Wk = (const float*)d_in[2];
  const float* Wv = (const float*)d_in[3];
  const float* Wp = (const float*)d_in[4];
  const float* bp = (const float*)d_in[5];

  char* ws = (char*)d_ws;
  _Float16* xh   = (_Float16*)(ws);                 // [4096,1024] f16   8 MB
  _Float16* wqkv = (_Float16*)(ws + 8388608);       // [3072,1024] f16   6 MB
  _Float16* wph  = (_Float16*)(ws + 14680064);      // [1024,1024] f16   2 MB
  _Float16* qkv  = (_Float16*)(ws + 16777216);      // [4096,3072] f16  24 MB
  float*    wdg  = (float*)   (ws + 41943040);      // [B,H,T] f32     256 KB
  float*    rinv = (float*)   (ws + 42205184);      // [B,H,T] f32     256 KB
  _Float16* ch   = (_Float16*)(ws + 42467328);      // [4096,1024] f16   8 MB

  float* out  = (float*)d_out;          // [B,T,C] f32
  float* wout = out + 4194304;          // [B,H,T,T] f32
  float* wpart = wout;                  // 16 MB scratch inside wout; pass B overwrites

  cast_all<<<4096, 256, 0, stream>>>(x, Wq, Wk, Wv, Wp, xh, wqkv, wph);
  gemm_bt<true, false><<<32 * 24, 256, 0, stream>>>(xh, wqkv, (void*)qkv, nullptr, 4096, 3072, 1024);
  attn_sums<<<528 * 32, 256, 0, stream>>>(qkv, wpart);
  sum_reduce<<<256, 256, 0, stream>>>(wpart, rinv);
  attn_write<<<32768, 256, 0, stream>>>(qkv, rinv, wout, wdg);
  diag_scale<<<2048, 256, 0, stream>>>(qkv, wdg, ch);
  gemm_bt<false, true><<<32 * 8, 256, 0, stream>>>(ch, wph, (void*)out, bp, 4096, 1024, 1024);
}

// Round 6
// 265.459 us; speedup vs baseline: 2.3016x; 1.0334x over previous
//
#include <hip/hip_runtime.h>
#include <hip/hip_bf16.h>
#include <hip/hip_fp16.h>

// B=2, T=2048, C=1024, H=16, HD=64
typedef _Float16 h8 __attribute__((ext_vector_type(8)));
typedef float fx4 __attribute__((ext_vector_type(4)));

__device__ __forceinline__ void load_lds16(const void* g, void* l) {
  __builtin_amdgcn_global_load_lds((const __attribute__((address_space(1))) void*)g,
                                   (__attribute__((address_space(3))) void*)l, 16, 0, 0);
}

// ---------------- cast f32 -> f16 for x, Wq, Wk, Wv, Wp ----------------
__global__ __launch_bounds__(256) void cast_all(
    const float* __restrict__ x, const float* __restrict__ Wq,
    const float* __restrict__ Wk, const float* __restrict__ Wv,
    const float* __restrict__ Wp,
    _Float16* __restrict__ xh, _Float16* __restrict__ wqkv,
    _Float16* __restrict__ wph) {
  int g = blockIdx.x * 256 + threadIdx.x;  // units of 8 elems, total 1048576
  const float* src; _Float16* dst;
  if (g < 524288)      { size_t o = (size_t)g * 8;            src = x  + o; dst = xh + o; }
  else if (g < 655360) { size_t o = (size_t)(g - 524288) * 8; src = Wq + o; dst = wqkv + o; }
  else if (g < 786432) { size_t o = (size_t)(g - 655360) * 8; src = Wk + o; dst = wqkv + 1048576 + o; }
  else if (g < 917504) { size_t o = (size_t)(g - 786432) * 8; src = Wv + o; dst = wqkv + 2097152 + o; }
  else                 { size_t o = (size_t)(g - 917504) * 8; src = Wp + o; dst = wph + o; }
  float4 a = *(const float4*)(src);
  float4 b = *(const float4*)(src + 4);
  h8 o;
  o[0]=(_Float16)a.x; o[1]=(_Float16)a.y; o[2]=(_Float16)a.z; o[3]=(_Float16)a.w;
  o[4]=(_Float16)b.x; o[5]=(_Float16)b.y; o[6]=(_Float16)b.z; o[7]=(_Float16)b.w;
  *(h8*)dst = o;
}

// ---------------- f16 BT-GEMM: C[m,n] = sum_k A[m,k]*B[n,k] (+bias) ----------------
template<bool OUT16, bool BIAS>
__global__ __launch_bounds__(256) void gemm_bt(
    const _Float16* __restrict__ A, const _Float16* __restrict__ Bm,
    void* __restrict__ Cv, const float* __restrict__ bias,
    int M, int N, int K) {
  __shared__ _Float16 As[8192];  // [128][64] f16, rows 128B, 8 chunks of 16B, chunk^=(row&7)
  __shared__ _Float16 Bs[8192];
  const int tid  = threadIdx.x;
  const int lane = tid & 63, w = tid >> 6;
  // XCD-chunked swizzle (grid divisible by 8)
  const int chunk = (int)gridDim.x >> 3;
  const int bid = ((int)blockIdx.x & 7) * chunk + ((int)blockIdx.x >> 3);
  const int nb = N >> 7;
  const int m0 = (bid / nb) << 7;
  const int n0 = (bid % nb) << 7;
  const int wm = (w >> 1) << 6, wn = (w & 1) << 6;
  fx4 acc[4][4] = {};
  const int fbase = w * 4096 + lane * 16;

  for (int k0 = 0; k0 < K; k0 += 64) {
    __syncthreads();
#pragma unroll
    for (int q = 0; q < 4; ++q) {
      int f = fbase + q * 1024;
      int row = f >> 7;
      int sch = ((f >> 4) & 7) ^ (row & 7);
      const _Float16* gA = A  + (size_t)(m0 + row) * K + k0 + sch * 8;
      const _Float16* gB = Bm + (size_t)(n0 + row) * K + k0 + sch * 8;
      load_lds16(gA, (char*)As + w * 4096 + q * 1024);
      load_lds16(gB, (char*)Bs + w * 4096 + q * 1024);
    }
    __syncthreads();

    h8 af[4][2], bf[4][2];
#pragma unroll
    for (int s4 = 0; s4 < 4; ++s4) {
#pragma unroll
      for (int kk = 0; kk < 2; ++kk) {
        int rowa = wm + s4 * 16 + (lane & 15);
        int cha  = (kk * 4 + (lane >> 4)) ^ (rowa & 7);
        af[s4][kk] = *(const h8*)((const char*)As + rowa * 128 + cha * 16);
        int rowb = wn + s4 * 16 + (lane & 15);
        int chb  = (kk * 4 + (lane >> 4)) ^ (rowb & 7);
        bf[s4][kk] = *(const h8*)((const char*)Bs + rowb * 128 + chb * 16);
      }
    }
#pragma unroll
    for (int ms = 0; ms < 4; ++ms)
#pragma unroll
      for (int ns = 0; ns < 4; ++ns) {
        acc[ms][ns] = __builtin_amdgcn_mfma_f32_16x16x32_f16(af[ms][0], bf[ns][0], acc[ms][ns], 0, 0, 0);
        acc[ms][ns] = __builtin_amdgcn_mfma_f32_16x16x32_f16(af[ms][1], bf[ns][1], acc[ms][ns], 0, 0, 0);
      }
  }

#pragma unroll
  for (int ms = 0; ms < 4; ++ms) {
    int row0 = m0 + wm + ms * 16 + ((lane >> 4) << 2);
#pragma unroll
    for (int ns = 0; ns < 4; ++ns) {
      int col = n0 + wn + ns * 16 + (lane & 15);
      float bv = BIAS ? bias[col] : 0.0f;
#pragma unroll
      for (int e = 0; e < 4; ++e) {
        float v = acc[ms][ns][e] + bv;
        if (OUT16) ((_Float16*)Cv)[(size_t)(row0 + e) * N + col] = (_Float16)v;
        else       ((float*)Cv)[(size_t)(row0 + e) * N + col] = v;
      }
    }
  }
}

// ================= tile-parallel attention =================
// tile (it,jt) of 64x64; rows = key i, cols = query j.

// Pass A: grid 32768 (all tiles). Lower tiles -> partial row sums into wpart;
// upper tiles -> nt zero-fill of wout (overlaps fills with sums compute).
// wpart layout [jt][bh*2048 + i] for coalesced sum_reduce reads.
__global__ __launch_bounds__(256) void attn_sums(
    const _Float16* __restrict__ qkv, float* __restrict__ wpart,
    float* __restrict__ wout) {
  // XCD-chunked swizzle: 32768 blocks = 8 * 4096
  const int bid = (blockIdx.x & 7) * 4096 + (blockIdx.x >> 3);
  const int jt = bid & 31, it = (bid >> 5) & 31;
  const int h = (bid >> 10) & 15, b = bid >> 14;
  const int bh = b * 16 + h;
  const int i0 = it << 6, j0 = jt << 6;
  const int tid = threadIdx.x;
  const int lane = tid & 63, w = tid >> 6;

  if (jt > it) {  // fully masked: zero-fill, full-row 256B segments per 16 lanes
    float* wrow = wout + (size_t)bh * 2048 * 2048;
    const int rl = lane >> 4, cw = (lane & 15) << 2;
    const fx4 z = {0.f, 0.f, 0.f, 0.f};
#pragma unroll
    for (int q = 0; q < 4; ++q) {
      const int r = w * 16 + q * 4 + rl;
      __builtin_nontemporal_store(z, (fx4*)(wrow + (size_t)(i0 + r) * 2048 + j0 + cw));
    }
    return;
  }

  const int lm = lane & 15, lg = lane >> 4;
  const int d0 = lg << 3;
  const bool diag = (it == jt);

  const _Float16* kbase = qkv + (size_t)b * 2048 * 3072 + 1024 + h * 64;
  const _Float16* qbase = qkv + (size_t)b * 2048 * 3072 + h * 64;

  const int irow = i0 + w * 16 + lm;
  h8 kf0 = *(const h8*)(kbase + (size_t)irow * 3072 + d0);
  h8 kf1 = *(const h8*)(kbase + (size_t)irow * 3072 + 32 + d0);

  const float slope = exp2f(-0.5f * (float)h);
  const int myrow = i0 + w * 16 + (lg << 2);

  float psum[4] = {0.f, 0.f, 0.f, 0.f};
#pragma unroll
  for (int sub = 0; sub < 4; ++sub) {
    const int j = j0 + (sub << 4) + lm;
    h8 qf0 = *(const h8*)(qbase + (size_t)j * 3072 + d0);
    h8 qf1 = *(const h8*)(qbase + (size_t)j * 3072 + 32 + d0);
    fx4 acc = {0.f, 0.f, 0.f, 0.f};
    acc = __builtin_amdgcn_mfma_f32_16x16x32_f16(kf0, qf0, acc, 0, 0, 0);
    acc = __builtin_amdgcn_mfma_f32_16x16x32_f16(kf1, qf1, acc, 0, 0, 0);
#pragma unroll
    for (int e = 0; e < 4; ++e) {
      const int i = myrow + e;
      if (!diag || j <= i) psum[e] += __expf(acc[e] - slope * (float)(i - j));
    }
  }
#pragma unroll
  for (int e = 0; e < 4; ++e) {
    float v = psum[e];
    v += __shfl_xor(v, 1);
    v += __shfl_xor(v, 2);
    v += __shfl_xor(v, 4);
    v += __shfl_xor(v, 8);
    if (lm == 0)
      wpart[(size_t)jt * 65536 + bh * 2048 + i0 + w * 16 + (lg << 2) + e] = v;
  }
}

// Pass A2: rinv[idx] = 1 / sum_{jt<=it} wpart[jt][idx]  (coalesced reads)
__global__ __launch_bounds__(256) void sum_reduce(
    const float* __restrict__ wpart, float* __restrict__ rinv) {
  const int idx = blockIdx.x * 256 + threadIdx.x;  // 65536
  const int i = idx & 2047;
  const int it = i >> 6;
  float s = 0.f;
  for (int jt = 0; jt <= it; ++jt) s += wpart[(size_t)jt * 65536 + idx];
  rinv[idx] = 1.0f / s;
}

// Pass B: lower tiles only (triangular grid). Write normalized weights
// (+ diagonal extract). LDS bounce, wave-private rows, nt coalesced stores.
__global__ __launch_bounds__(256) void attn_write(
    const _Float16* __restrict__ qkv, const float* __restrict__ rinv,
    float* __restrict__ wout, float* __restrict__ wdiag) {
  // XCD-chunked swizzle: 16896 blocks = 8 * 2112
  const int bid = (blockIdx.x & 7) * 2112 + (blockIdx.x >> 3);
  const int u = bid % 528;
  const int bh = bid / 528;
  int it = (int)((sqrtf(8.0f * (float)u + 1.0f) - 1.0f) * 0.5f);
  while ((it + 1) * (it + 2) / 2 <= u) ++it;
  while (it * (it + 1) / 2 > u) --it;
  const int jt = u - it * (it + 1) / 2;
  const int b = bh >> 4, h = bh & 15;
  const int i0 = it << 6, j0 = jt << 6;
  const int tid = threadIdx.x;
  const int lane = tid & 63, w = tid >> 6;
  float* wrow = wout + (size_t)bh * 2048 * 2048;

  __shared__ float tile[64 * 68];  // stride 68: aligned float4 rows, ~2-way banks max

  const int lm = lane & 15, lg = lane >> 4;
  const int d0 = lg << 3;
  const bool diag = (it == jt);

  const _Float16* kbase = qkv + (size_t)b * 2048 * 3072 + 1024 + h * 64;
  const _Float16* qbase = qkv + (size_t)b * 2048 * 3072 + h * 64;

  const int irow = i0 + w * 16 + lm;
  h8 kf0 = *(const h8*)(kbase + (size_t)irow * 3072 + d0);
  h8 kf1 = *(const h8*)(kbase + (size_t)irow * 3072 + 32 + d0);

  const float slope = exp2f(-0.5f * (float)h);
  const int myrow = i0 + w * 16 + (lg << 2);

  float rv[4];
#pragma unroll
  for (int e = 0; e < 4; ++e) rv[e] = rinv[bh * 2048 + myrow + e];

  float* wd = wdiag + bh * 2048;
#pragma unroll
  for (int sub = 0; sub < 4; ++sub) {
    const int j = j0 + (sub << 4) + lm;
    h8 qf0 = *(const h8*)(qbase + (size_t)j * 3072 + d0);
    h8 qf1 = *(const h8*)(qbase + (size_t)j * 3072 + 32 + d0);
    fx4 acc = {0.f, 0.f, 0.f, 0.f};
    acc = __builtin_amdgcn_mfma_f32_16x16x32_f16(kf0, qf0, acc, 0, 0, 0);
    acc = __builtin_amdgcn_mfma_f32_16x16x32_f16(kf1, qf1, acc, 0, 0, 0);
#pragma unroll
    for (int e = 0; e < 4; ++e) {
      const int i = myrow + e;
      float p = (!diag || j <= i) ? __expf(acc[e] - slope * (float)(i - j)) * rv[e] : 0.0f;
      tile[(w * 16 + (lg << 2) + e) * 68 + (sub << 4) + lm] = p;
      if (diag && j == i) wd[i] = p;
    }
  }
  // No __syncthreads: wave w wrote exactly rows w*16..w*16+15; it alone reads them.
  const int rl = lane >> 4, cw = (lane & 15) << 2;
#pragma unroll
  for (int q = 0; q < 4; ++q) {
    const int r = w * 16 + q * 4 + rl;
    fx4 v = *(const fx4*)&tile[r * 68 + cw];
    __builtin_nontemporal_store(v, (fx4*)(wrow + (size_t)(i0 + r) * 2048 + j0 + cw));
  }
}

// ---------------- concat[b,t,h*64+d] = wdiag[b,h,t] * v[b,t,h,d] ----------------
__global__ __launch_bounds__(256) void diag_scale(
    const _Float16* __restrict__ qkv, const float* __restrict__ wdiag,
    _Float16* __restrict__ ch) {
  const int g = blockIdx.x * 256 + threadIdx.x;  // 524288 total (8 elems each)
  const int c = (g << 3) & 1023;
  const int bt = g >> 7;
  const int hh = c >> 6;
  const int b = bt >> 11, t = bt & 2047;
  const float wv = wdiag[((b << 4) + hh) * 2048 + t];
  h8 v = *(const h8*)(qkv + (size_t)bt * 3072 + 2048 + c);
  h8 o;
#pragma unroll
  for (int e = 0; e < 8; ++e) o[e] = (_Float16)(wv * (float)v[e]);
  *(h8*)(ch + (size_t)bt * 1024 + c) = o;
}

// ---------------- launch ----------------
extern "C" void kernel_launch(void* const* d_in, const int* in_sizes, int n_in,
                              void* d_out, int out_size, void* d_ws, size_t ws_size,
                              hipStream_t stream) {
  (void)in_sizes; (void)n_in; (void)out_size; (void)ws_size;
  const float* x  = (const float*)d_in[0];
  const float* Wq = (const float*)d_in[1];
  const float* Wk = (const float*)d_in[2];
  const float* Wv = (const float*)d_in[3];
  const float* Wp = (const float*)d_in[4];
  const float* bp = (const float*)d_in[5];

  char* ws = (char*)d_ws;
  _Float16* xh   = (_Float16*)(ws);                 // [4096,1024] f16   8 MB (dead after gemm1)
  float*    wpart= (float*)   (ws);                 // [32][65536] f32   8 MB (reuses xh region)
  _Float16* wqkv = (_Float16*)(ws + 8388608);       // [3072,1024] f16   6 MB
  _Float16* wph  = (_Float16*)(ws + 14680064);      // [1024,1024] f16   2 MB
  _Float16* qkv  = (_Float16*)(ws + 16777216);      // [4096,3072] f16  24 MB
  float*    wdg  = (float*)   (ws + 41943040);      // [B,H,T] f32     256 KB
  float*    rinv = (float*)   (ws + 42205184);      // [B,H,T] f32     256 KB
  _Float16* ch   = (_Float16*)(ws + 42467328);      // [4096,1024] f16   8 MB

  float* out  = (float*)d_out;          // [B,T,C] f32
  float* wout = out + 4194304;          // [B,H,T,T] f32

  cast_all<<<4096, 256, 0, stream>>>(x, Wq, Wk, Wv, Wp, xh, wqkv, wph);
  gemm_bt<true, false><<<32 * 24, 256, 0, stream>>>(xh, wqkv, (void*)qkv, nullptr, 4096, 3072, 1024);
  attn_sums<<<32768, 256, 0, stream>>>(qkv, wpart, wout);   // sums + upper zero-fill
  sum_reduce<<<256, 256, 0, stream>>>(wpart, rinv);
  attn_write<<<528 * 32, 256, 0, stream>>>(qkv, rinv, wout, wdg);
  diag_scale<<<2048, 256, 0, stream>>>(qkv, wdg, ch);
  gemm_bt<false, true><<<32 * 8, 256, 0, stream>>>(ch, wph, (void*)out, bp, 4096, 1024, 1024);
}

// Round 8
// 246.874 us; speedup vs baseline: 2.4749x; 1.0753x over previous
//
#include <hip/hip_runtime.h>
#include <hip/hip_bf16.h>
#include <hip/hip_fp16.h>

// B=2, T=2048, C=1024, H=16, HD=64
typedef _Float16 h8 __attribute__((ext_vector_type(8)));
typedef float fx4 __attribute__((ext_vector_type(4)));

__device__ __forceinline__ void load_lds16(const void* g, void* l) {
  __builtin_amdgcn_global_load_lds((const __attribute__((address_space(1))) void*)g,
                                   (__attribute__((address_space(3))) void*)l, 16, 0, 0);
}

// ---------------- cast f32 -> f16 for x, Wq, Wk, Wv, Wp ----------------
__global__ __launch_bounds__(256) void cast_all(
    const float* __restrict__ x, const float* __restrict__ Wq,
    const float* __restrict__ Wk, const float* __restrict__ Wv,
    const float* __restrict__ Wp,
    _Float16* __restrict__ xh, _Float16* __restrict__ wqkv,
    _Float16* __restrict__ wph) {
  int g = blockIdx.x * 256 + threadIdx.x;  // units of 8 elems, total 1048576
  const float* src; _Float16* dst;
  if (g < 524288)      { size_t o = (size_t)g * 8;            src = x  + o; dst = xh + o; }
  else if (g < 655360) { size_t o = (size_t)(g - 524288) * 8; src = Wq + o; dst = wqkv + o; }
  else if (g < 786432) { size_t o = (size_t)(g - 655360) * 8; src = Wk + o; dst = wqkv + 1048576 + o; }
  else if (g < 917504) { size_t o = (size_t)(g - 786432) * 8; src = Wv + o; dst = wqkv + 2097152 + o; }
  else                 { size_t o = (size_t)(g - 917504) * 8; src = Wp + o; dst = wph + o; }
  float4 a = *(const float4*)(src);
  float4 b = *(const float4*)(src + 4);
  h8 o;
  o[0]=(_Float16)a.x; o[1]=(_Float16)a.y; o[2]=(_Float16)a.z; o[3]=(_Float16)a.w;
  o[4]=(_Float16)b.x; o[5]=(_Float16)b.y; o[6]=(_Float16)b.z; o[7]=(_Float16)b.w;
  *(h8*)dst = o;
}

// ---------------- f16 BT-GEMM: C[m,n] = sum_k A[m,k]*B[n,k] (+bias) ----------------
template<bool OUT16, bool BIAS>
__global__ __launch_bounds__(256) void gemm_bt(
    const _Float16* __restrict__ A, const _Float16* __restrict__ Bm,
    void* __restrict__ Cv, const float* __restrict__ bias,
    int M, int N, int K) {
  __shared__ _Float16 As[8192];  // [128][64] f16, rows 128B, 8 chunks of 16B, chunk^=(row&7)
  __shared__ _Float16 Bs[8192];
  const int tid  = threadIdx.x;
  const int lane = tid & 63, w = tid >> 6;
  // XCD-chunked swizzle (grid divisible by 8)
  const int chunk = (int)gridDim.x >> 3;
  const int bid = ((int)blockIdx.x & 7) * chunk + ((int)blockIdx.x >> 3);
  const int nb = N >> 7;
  const int m0 = (bid / nb) << 7;
  const int n0 = (bid % nb) << 7;
  const int wm = (w >> 1) << 6, wn = (w & 1) << 6;
  fx4 acc[4][4] = {};
  const int fbase = w * 4096 + lane * 16;

  for (int k0 = 0; k0 < K; k0 += 64) {
    __syncthreads();
#pragma unroll
    for (int q = 0; q < 4; ++q) {
      int f = fbase + q * 1024;
      int row = f >> 7;
      int sch = ((f >> 4) & 7) ^ (row & 7);
      const _Float16* gA = A  + (size_t)(m0 + row) * K + k0 + sch * 8;
      const _Float16* gB = Bm + (size_t)(n0 + row) * K + k0 + sch * 8;
      load_lds16(gA, (char*)As + w * 4096 + q * 1024);
      load_lds16(gB, (char*)Bs + w * 4096 + q * 1024);
    }
    __syncthreads();

    h8 af[4][2], bf[4][2];
#pragma unroll
    for (int s4 = 0; s4 < 4; ++s4) {
#pragma unroll
      for (int kk = 0; kk < 2; ++kk) {
        int rowa = wm + s4 * 16 + (lane & 15);
        int cha  = (kk * 4 + (lane >> 4)) ^ (rowa & 7);
        af[s4][kk] = *(const h8*)((const char*)As + rowa * 128 + cha * 16);
        int rowb = wn + s4 * 16 + (lane & 15);
        int chb  = (kk * 4 + (lane >> 4)) ^ (rowb & 7);
        bf[s4][kk] = *(const h8*)((const char*)Bs + rowb * 128 + chb * 16);
      }
    }
#pragma unroll
    for (int ms = 0; ms < 4; ++ms)
#pragma unroll
      for (int ns = 0; ns < 4; ++ns) {
        acc[ms][ns] = __builtin_amdgcn_mfma_f32_16x16x32_f16(af[ms][0], bf[ns][0], acc[ms][ns], 0, 0, 0);
        acc[ms][ns] = __builtin_amdgcn_mfma_f32_16x16x32_f16(af[ms][1], bf[ns][1], acc[ms][ns], 0, 0, 0);
      }
  }

#pragma unroll
  for (int ms = 0; ms < 4; ++ms) {
    int row0 = m0 + wm + ms * 16 + ((lane >> 4) << 2);
#pragma unroll
    for (int ns = 0; ns < 4; ++ns) {
      int col = n0 + wn + ns * 16 + (lane & 15);
      float bv = BIAS ? bias[col] : 0.0f;
#pragma unroll
      for (int e = 0; e < 4; ++e) {
        float v = acc[ms][ns][e] + bv;
        if (OUT16) ((_Float16*)Cv)[(size_t)(row0 + e) * N + col] = (_Float16)v;
        else       ((float*)Cv)[(size_t)(row0 + e) * N + col] = v;
      }
    }
  }
}

// ================= fused single-pass attention =================
// Block = (bh, it): 16 key rows i0..i0+15, ALL query cols j.
// Phase 1: waves split j-tiles; LOGIT l = qk - slope*(i-j) stored as f16 in
//          LDS (abs err ~|l|*5e-4 -> weight rel err <1% for any weight >1e-4;
//          masked slots = -60000). Row sums of exp(l) accumulated in f32.
// Phase 2 (after one barrier): wave w streams rows 4w..4w+3 as full
//          2048-f32 nt-coalesced rows: exp(l)*rinv for j<=i, zeros beyond.
// LDS 66.3 KB -> 2 blocks/CU. Grid 4096 = 32 bh * 128 it, XCD-chunked.
__global__ __launch_bounds__(256, 2) void attn_fused(
    const _Float16* __restrict__ qkv, float* __restrict__ wout,
    float* __restrict__ wdiag) {
  __shared__ _Float16 p16[16 * 2064];  // row stride 2064 f16 (4128 B)
  __shared__ float wsum[4 * 16];       // [wave][row]

  const int n = (blockIdx.x & 7) * 512 + (blockIdx.x >> 3);
  const int bh = n >> 7, it = n & 127;
  const int b = bh >> 4, h = bh & 15;
  const int i0 = it << 4;
  const int tid = threadIdx.x;
  const int lane = tid & 63, w = tid >> 6;
  const int lm = lane & 15, lg = lane >> 4;
  const int d0 = lg << 3;

  const _Float16* kbase = qkv + (size_t)b * 2048 * 3072 + 1024 + h * 64;
  const _Float16* qbase = qkv + (size_t)b * 2048 * 3072 + h * 64;

  // K fragment (rows i0..i0+15) — same for all waves
  h8 kf0 = *(const h8*)(kbase + (size_t)(i0 + lm) * 3072 + d0);
  h8 kf1 = *(const h8*)(kbase + (size_t)(i0 + lm) * 3072 + 32 + d0);

  const float slope = exp2f(-0.5f * (float)h);

  float psum[4] = {0.f, 0.f, 0.f, 0.f};

  for (int jt = w; jt <= it; jt += 4) {
    const int j = (jt << 4) + lm;
    h8 qf0 = *(const h8*)(qbase + (size_t)j * 3072 + d0);
    h8 qf1 = *(const h8*)(qbase + (size_t)j * 3072 + 32 + d0);
    fx4 acc = {0.f, 0.f, 0.f, 0.f};
    acc = __builtin_amdgcn_mfma_f32_16x16x32_f16(kf0, qf0, acc, 0, 0, 0);
    acc = __builtin_amdgcn_mfma_f32_16x16x32_f16(kf1, qf1, acc, 0, 0, 0);
    const bool diag = (jt == it);
#pragma unroll
    for (int e = 0; e < 4; ++e) {
      const int il = (lg << 2) + e;
      const int i = i0 + il;
      const bool live = (!diag || j <= i);
      float l = acc[e] - slope * (float)(i - j);
      if (live) psum[e] += __expf(l);
      p16[il * 2064 + j] = (_Float16)(live ? l : -60000.f);
    }
  }
#pragma unroll
  for (int e = 0; e < 4; ++e) {
    float v = psum[e];
    v += __shfl_xor(v, 1);
    v += __shfl_xor(v, 2);
    v += __shfl_xor(v, 4);
    v += __shfl_xor(v, 8);
    if (lm == 0) wsum[w * 16 + (lg << 2) + e] = v;
  }
  __syncthreads();

  float* wrow = wout + (size_t)bh * 4194304;
  float* wd = wdiag + bh * 2048;
#pragma unroll
  for (int q = 0; q < 4; ++q) {
    const int r = (w << 2) + q;
    const int i = i0 + r;
    const float rv = 1.0f / (wsum[r] + wsum[16 + r] + wsum[32 + r] + wsum[48 + r]);
    float* obase = wrow + (size_t)i * 2048;
#pragma unroll
    for (int c = 0; c < 4; ++c) {
      const int jb = (c << 9) + (lane << 3);
      fx4 lo = {0.f, 0.f, 0.f, 0.f}, hi = {0.f, 0.f, 0.f, 0.f};
      if (jb <= i) {
        h8 pv = *(const h8*)&p16[r * 2064 + jb];
#pragma unroll
        for (int e2 = 0; e2 < 8; ++e2) {
          float wv = (jb + e2 <= i) ? __expf((float)pv[e2]) * rv : 0.f;
          if (e2 < 4) lo[e2] = wv; else hi[e2 - 4] = wv;
          if (jb + e2 == i) wd[i] = wv;  // diagonal (static index)
        }
      }
      __builtin_nontemporal_store(lo, (fx4*)(obase + jb));
      __builtin_nontemporal_store(hi, (fx4*)(obase + jb + 4));
    }
  }
}

// ---------------- concat[b,t,h*64+d] = wdiag[b,h,t] * v[b,t,h,d] ----------------
__global__ __launch_bounds__(256) void diag_scale(
    const _Float16* __restrict__ qkv, const float* __restrict__ wdiag,
    _Float16* __restrict__ ch) {
  const int g = blockIdx.x * 256 + threadIdx.x;  // 524288 total (8 elems each)
  const int c = (g << 3) & 1023;
  const int bt = g >> 7;
  const int hh = c >> 6;
  const int b = bt >> 11, t = bt & 2047;
  const float wv = wdiag[((b << 4) + hh) * 2048 + t];
  h8 v = *(const h8*)(qkv + (size_t)bt * 3072 + 2048 + c);
  h8 o;
#pragma unroll
  for (int e = 0; e < 8; ++e) o[e] = (_Float16)(wv * (float)v[e]);
  *(h8*)(ch + (size_t)bt * 1024 + c) = o;
}

// ---------------- launch ----------------
extern "C" void kernel_launch(void* const* d_in, const int* in_sizes, int n_in,
                              void* d_out, int out_size, void* d_ws, size_t ws_size,
                              hipStream_t stream) {
  (void)in_sizes; (void)n_in; (void)out_size; (void)ws_size;
  const float* x  = (const float*)d_in[0];
  const float* Wq = (const float*)d_in[1];
  const float* Wk = (const float*)d_in[2];
  const float* Wv = (const float*)d_in[3];
  const float* Wp = (const float*)d_in[4];
  const float* bp = (const float*)d_in[5];

  char* ws = (char*)d_ws;
  _Float16* xh   = (_Float16*)(ws);                 // [4096,1024] f16   8 MB
  _Float16* wqkv = (_Float16*)(ws + 8388608);       // [3072,1024] f16   6 MB
  _Float16* wph  = (_Float16*)(ws + 14680064);      // [1024,1024] f16   2 MB
  _Float16* qkv  = (_Float16*)(ws + 16777216);      // [4096,3072] f16  24 MB
  float*    wdg  = (float*)   (ws + 41943040);      // [B,H,T] f32     256 KB
  _Float16* ch   = (_Float16*)(ws + 42467328);      // [4096,1024] f16   8 MB

  float* out  = (float*)d_out;          // [B,T,C] f32
  float* wout = out + 4194304;          // [B,H,T,T] f32

  cast_all<<<4096, 256, 0, stream>>>(x, Wq, Wk, Wv, Wp, xh, wqkv, wph);
  gemm_bt<true, false><<<32 * 24, 256, 0, stream>>>(xh, wqkv, (void*)qkv, nullptr, 4096, 3072, 1024);
  attn_fused<<<4096, 256, 0, stream>>>(qkv, wout, wdg);
  diag_scale<<<2048, 256, 0, stream>>>(qkv, wdg, ch);
  gemm_bt<false, true><<<32 * 8, 256, 0, stream>>>(ch, wph, (void*)out, bp, 4096, 1024, 1024);
}